// Round 1
// baseline (256.025 us; speedup 1.0000x reference)
//
#include <hip/hip_runtime.h>
#include <stdint.h>

#define S_LEN 512
#define I_DIM 28
#define H_DIM 128
#define O_DIM 28
#define BT    16   // batch rows per block

typedef __attribute__((ext_vector_type(8))) short bf16x8;
typedef __attribute__((ext_vector_type(4))) float f32x4;

__device__ __forceinline__ short f2bf(float f) {
    unsigned u = __float_as_uint(f);
    u = (u + 0x7fffu + ((u >> 16) & 1u)) >> 16;   // RNE, inputs are finite
    return (short)u;
}
__device__ __forceinline__ float bf2f(unsigned short u) {
    return __uint_as_float(((unsigned)u) << 16);
}
__device__ __forceinline__ float fast_tanh(float a) {
    // tanh(a) = 1 - 2/(1+exp(2a)); saturates correctly at +-inf, exact 0 at 0
    float e = __expf(2.0f * a);
    return 1.0f - 2.0f / (1.0f + e);
}

__global__ __launch_bounds__(512, 1) void rnn_fused(
    const float* __restrict__ x,
    const float* __restrict__ W_ih, const float* __restrict__ b_ih,
    const float* __restrict__ W_hh, const float* __restrict__ b_hh,
    const float* __restrict__ W_ho, const float* __restrict__ b_ho,
    float* __restrict__ out)
{
    const int tid  = threadIdx.x;
    const int wave = tid >> 6;         // 0..7 -> output column tile j0 = wave*16
    const int lane = tid & 63;
    const int l15  = lane & 15;
    const int lk   = lane >> 4;        // 0..3 (k-group within MFMA fragment)
    const int r0   = blockIdx.x * BT;  // batch-row base for this block

    __shared__ __align__(16) unsigned short hbuf[2][BT * H_DIM]; // bf16, XOR-swizzled, 8KB
    __shared__ bf16x8 xstage[16][64];                            // x A-frag ring, 16KB

    // ---- constant B fragments (held in registers for all 512 steps) ----
    const int jcol = wave * 16 + l15;
    // W_hh: B[k][j], k = kk*32 + lk*8 + e
    bf16x8 bw[4];
    #pragma unroll
    for (int kk = 0; kk < 4; ++kk) {
        #pragma unroll
        for (int e = 0; e < 8; ++e)
            bw[kk][e] = f2bf(W_hh[(kk * 32 + lk * 8 + e) * H_DIM + jcol]);
    }
    // W_ih: K=28 zero-padded to 32
    bf16x8 bx;
    #pragma unroll
    for (int e = 0; e < 8; ++e) {
        int k = lk * 8 + e;
        bx[e] = (k < I_DIM) ? f2bf(W_ih[k * H_DIM + jcol]) : (short)0;
    }
    const float bias = b_ih[jcol] + b_hh[jcol];

    // ---- per-lane LDS byte offsets ----
    // h A-frag reads: row=l15, k = kk*32 + lk*8 (16B each)
    int ha_off[4];
    #pragma unroll
    for (int kk = 0; kk < 4; ++kk)
        ha_off[kk] = ((l15 * 256) + (kk * 64) + (lk * 16)) ^ ((l15 & 7) << 4);
    // h writes from C-frag: row = lk*4 + r, col = jcol
    int hw_off[4];
    #pragma unroll
    for (int r = 0; r < 4; ++r) {
        int row = lk * 4 + r;
        hw_off[r] = (row * 256 + jcol * 2) ^ ((row & 7) << 4);
    }

    // zero-init h (h0 = 0)
    for (int i = tid; i < BT * H_DIM; i += 512) hbuf[0][i] = 0;

    // ---- stage x frames 0..7 (wave w stages frame w) ----
    const float* xbase = x + (size_t)(r0 + l15) * S_LEN * I_DIM + lk * 8;
    const bool hasHi = (lk < 3);   // k-group 3 covers k=24..31; only 24..27 valid
    {
        const float* src = xbase + wave * I_DIM;
        float4 lo = *(const float4*)src;
        float4 hi = hasHi ? *(const float4*)(src + 4) : make_float4(0.f, 0.f, 0.f, 0.f);
        bf16x8 f;
        f[0]=f2bf(lo.x); f[1]=f2bf(lo.y); f[2]=f2bf(lo.z); f[3]=f2bf(lo.w);
        f[4]=f2bf(hi.x); f[5]=f2bf(hi.y); f[6]=f2bf(hi.z); f[7]=f2bf(hi.w);
        xstage[wave][lane] = f;
    }
    asm volatile("s_waitcnt lgkmcnt(0)" ::: "memory");
    __builtin_amdgcn_s_barrier();
    asm volatile("" ::: "memory");

    // ---- time loop: 8 steps per outer iteration ----
    for (int t8 = 0; t8 < S_LEN; t8 += 8) {
        // wave w issues global loads for frame t8+8+w (consumed next block)
        const int tf = t8 + 8 + wave;
        float4 pf_lo = make_float4(0.f,0.f,0.f,0.f), pf_hi = make_float4(0.f,0.f,0.f,0.f);
        if (tf < S_LEN) {
            const float* src = xbase + (size_t)tf * I_DIM;
            pf_lo = *(const float4*)src;
            if (hasHi) pf_hi = *(const float4*)(src + 4);
        }
        // pull this block's 8 x A-frags from LDS into registers
        bf16x8 axf[8];
        #pragma unroll
        for (int p = 0; p < 8; ++p)
            axf[p] = xstage[(t8 + p) & 15][lane];

        #pragma unroll
        for (int p = 0; p < 8; ++p) {
            const char* rb = (const char*)hbuf[p & 1];        // read h_{t-1}
            char*       wb = (char*)hbuf[(p & 1) ^ 1];        // write h_t

            f32x4 acc = {0.f, 0.f, 0.f, 0.f};
            acc = __builtin_amdgcn_mfma_f32_16x16x32_bf16(axf[p], bx, acc, 0, 0, 0);
            #pragma unroll
            for (int kk = 0; kk < 4; ++kk) {
                bf16x8 ah = *(const bf16x8*)(rb + ha_off[kk]);
                acc = __builtin_amdgcn_mfma_f32_16x16x32_bf16(ah, bw[kk], acc, 0, 0, 0);
            }
            #pragma unroll
            for (int r = 0; r < 4; ++r) {
                float hv = fast_tanh(acc[r] + bias);
                *(unsigned short*)(wb + hw_off[r]) = (unsigned short)f2bf(hv);
            }
            // write next-block x frame late (HBM latency covered by ~6 steps)
            if (p == 6 && tf < S_LEN) {
                bf16x8 f;
                f[0]=f2bf(pf_lo.x); f[1]=f2bf(pf_lo.y); f[2]=f2bf(pf_lo.z); f[3]=f2bf(pf_lo.w);
                f[4]=f2bf(pf_hi.x); f[5]=f2bf(pf_hi.y); f[6]=f2bf(pf_hi.z); f[7]=f2bf(pf_hi.w);
                xstage[tf & 15][lane] = f;
            }
            asm volatile("s_waitcnt lgkmcnt(0)" ::: "memory");
            __builtin_amdgcn_s_barrier();
            asm volatile("" ::: "memory");
        }
    }

    // ---- epilogue: out[b][o] = h_512[b][:] @ W_ho[:,o] + b_ho[o] ----
    // t=511 (odd) wrote hbuf[0]
    if (tid < BT * O_DIM) {
        const int b = tid / O_DIM;
        const int o = tid - b * O_DIM;
        float sum = b_ho[o];
        const char* hb = (const char*)hbuf[0];
        for (int j = 0; j < H_DIM; ++j) {
            int off = (b * 256 + j * 2) ^ ((b & 7) << 4);
            sum += bf2f(*(const unsigned short*)(hb + off)) * W_ho[j * O_DIM + o];
        }
        out[(size_t)(r0 + b) * O_DIM + o] = sum;
    }
}

extern "C" void kernel_launch(void* const* d_in, const int* in_sizes, int n_in,
                              void* d_out, int out_size, void* d_ws, size_t ws_size,
                              hipStream_t stream) {
    const float* x    = (const float*)d_in[0];
    const float* W_ih = (const float*)d_in[1];
    const float* b_ih = (const float*)d_in[2];
    const float* W_hh = (const float*)d_in[3];
    const float* b_hh = (const float*)d_in[4];
    const float* W_ho = (const float*)d_in[5];
    const float* b_ho = (const float*)d_in[6];
    const int B = in_sizes[0] / (S_LEN * I_DIM);   // 4096
    rnn_fused<<<B / BT, 512, 0, stream>>>(x, W_ih, b_ih, W_hh, b_hh, W_ho, b_ho,
                                          (float*)d_out);
}